// Round 1
// baseline (386.468 us; speedup 1.0000x reference)
//
#include <hip/hip_runtime.h>

// Problem constants
#define NROWS 8192
#define INF   4096
#define OUTF  4096
#define G     1024          // INF / 4

typedef _Float16 f16x8 __attribute__((ext_vector_type(8)));
typedef float    f32x4 __attribute__((ext_vector_type(4)));

// ws layout:
//   [0..16)                  float scales[3]: [0]=act_scale, [1]=127/absmax, [2]=act_scale*0.25*wscale
//   [16 .. 16+8192)          2048 float block-partial maxes
//   [8208 ..)                x_sum f16 [NROWS][G]   (16 MB)
//   [8208 + NROWS*G*2 ..)    w_sum f16 [OUTF][G]    (8 MB)

// ---------- Kernel 1: absmax partials (x) + group-sum (w), one pass ----------
// blocks [0,2048): absmax over x, 16 float4/thread
// blocks [2048,3072): w group-sums, 16 float4/thread (scale-independent)
__global__ void pass1(const float4* __restrict__ x,
                      const float4* __restrict__ w,
                      float* __restrict__ partial,
                      _Float16* __restrict__ ws) {
    const int t = threadIdx.x;
    const int b = blockIdx.x;
    if (b < 2048) {
        const int stride = 2048 * 256;
        int i = b * 256 + t;
        float m = 0.f;
        #pragma unroll 4
        for (int it = 0; it < 16; ++it, i += stride) {
            float4 v = x[i];
            m = fmaxf(m, fmaxf(fmaxf(fabsf(v.x), fabsf(v.y)),
                               fmaxf(fabsf(v.z), fabsf(v.w))));
        }
        for (int off = 32; off; off >>= 1)
            m = fmaxf(m, __shfl_down(m, off));
        __shared__ float wm[4];
        int lane = t & 63, wave = t >> 6;
        if (lane == 0) wm[wave] = m;
        __syncthreads();
        if (t == 0)
            partial[b] = fmaxf(fmaxf(wm[0], wm[1]), fmaxf(wm[2], wm[3]));
    } else {
        // 1024 blocks * 256 threads * 16 iters = 4194304 float4 groups of w
        int i = (b - 2048) * 4096 + t;
        #pragma unroll 4
        for (int it = 0; it < 16; ++it, i += 256) {
            float4 v = w[i];
            ws[i] = (_Float16)(v.x + v.y + v.z + v.w);  // integer in [-4,4]: exact
        }
    }
}

// ---------- Kernel 2: reduce partials -> all scales ----------
__global__ void absmax_final(const float* __restrict__ partial,
                             const float* __restrict__ wscale,
                             float* __restrict__ sc) {
    int t = threadIdx.x;  // 256 threads
    float m = 0.f;
    #pragma unroll
    for (int u = 0; u < 8; ++u)
        m = fmaxf(m, partial[t + u * 256]);
    for (int off = 32; off; off >>= 1)
        m = fmaxf(m, __shfl_down(m, off));
    __shared__ float wm[4];
    int lane = t & 63, wave = t >> 6;
    if (lane == 0) wm[wave] = m;
    __syncthreads();
    if (t == 0) {
        float bm = fmaxf(fmaxf(wm[0], wm[1]), fmaxf(wm[2], wm[3]));
        float s = bm * (1.0f / 127.0f);
        sc[0] = s;                       // act_scale
        sc[1] = 127.0f / bm;             // quant reciprocal (mul, not div, in hot loop)
        sc[2] = s * 0.25f * wscale[0];   // fused epilogue scale for GEMM
    }
}

// ---------- Kernel 3: quantize + group-sum x ----------
// No clamps: absmax construction bounds |v*inv| <= 127*(1+eps) < 127.5, rint is exact.
__global__ void xquant(const float4* __restrict__ x,
                       const float* __restrict__ sc,
                       _Float16* __restrict__ xs) {
    const float inv = sc[1];
    int i0 = blockIdx.x * 512 + threadIdx.x;
    #pragma unroll
    for (int u = 0; u < 2; ++u) {
        int i = i0 + u * 256;
        float4 v = x[i];
        // per-group sum of quantized values: integer in [-512,508], exact in f16
        xs[i] = (_Float16)(rintf(v.x * inv) + rintf(v.y * inv) +
                           rintf(v.z * inv) + rintf(v.w * inv));
    }
}

// ---------- Kernel 4: f16 MFMA GEMM, 256x128 tile, double-buffered, swizzled LDS ----------
#define BM 256
#define BN 128
#define BK 32

__device__ __forceinline__ void async_copy16(const void* g, void* l) {
    __builtin_amdgcn_global_load_lds(
        (const __attribute__((address_space(1))) unsigned int*)g,
        (__attribute__((address_space(3))) unsigned int*)l,
        16, 0, 0);
}

__global__ __launch_bounds__(256, 2) void gemm_kernel(
    const _Float16* __restrict__ A,
    const _Float16* __restrict__ B,
    const float* __restrict__ bias,
    const float* __restrict__ sc,
    float* __restrict__ out) {

    // Double-buffered: 2 x (16 KB A + 8 KB B) = 48 KB -> still 2 blocks/CU.
    __shared__ alignas(16) _Float16 As[2][BM * BK];
    __shared__ alignas(16) _Float16 Bs[2][BN * BK];

    const int t = threadIdx.x;
    const int lane = t & 63;
    const int wave = t >> 6;
    const int wm = (wave >> 1) * 128;   // wave tile: 128 rows x 64 cols
    const int wn = (wave & 1) * 64;

    const long rowA0 = (long)blockIdx.y * BM;
    const long rowB0 = (long)blockIdx.x * BN;

    f32x4 acc[8][4] = {};

    // Staging: chunk = 1 KB = 16 rows x 32 f16. Lane l covers row srow, 16 B at scol.
    // LDS dest is linear (global_load_lds writes base + lane*16); the bank-conflict
    // swizzle is applied on the GLOBAL source column instead (both-sides rule):
    //   phys_col8 = col8 ^ ((row>>1)&3)<<3   (col8 in units of 8 f16 = 16 B)
    // For staging, row = c*16 + (lane>>2), so (row>>1)&3 == (lane>>3)&3.
    const int srow = lane >> 2;
    const int scol = ((lane & 3) << 3) ^ (((lane >> 3) & 3) << 3);
    // For fragment reads, row low bits = lane&15, so (row>>1)&3 == (lane>>1)&3.
    const int swzR = ((lane >> 1) & 3) << 3;

    auto stage = [&](int buf, int k0) {
        #pragma unroll
        for (int i = 0; i < 6; ++i) {
            const int c = wave * 6 + i;       // wave-uniform chunk id, 24 = 16 A + 8 B
            if (c < 16) {
                const int row = c * 16 + srow;
                async_copy16(A + (rowA0 + row) * (long)G + k0 + scol, &As[buf][c * 512]);
            } else {
                const int row = (c - 16) * 16 + srow;
                async_copy16(B + (rowB0 + row) * (long)G + k0 + scol, &Bs[buf][(c - 16) * 512]);
            }
        }
    };

    stage(0, 0);
    __syncthreads();   // compiler drains vmcnt(0) before s_barrier

    int cur = 0;
    for (int ks = 0; ks < G / BK; ++ks) {
        // T3-minimum: issue next tile's stage BEFORE compute of current tile,
        // so HBM/L2 latency hides under ds_read + MFMA. One barrier per K-step.
        if (ks + 1 < G / BK) stage(cur ^ 1, (ks + 1) * BK);

        f16x8 af[8], bf[4];
        #pragma unroll
        for (int mi = 0; mi < 8; ++mi)
            af[mi] = *(const f16x8*)&As[cur][(wm + mi * 16 + (lane & 15)) * BK
                                            + (((lane >> 4) * 8) ^ swzR)];
        #pragma unroll
        for (int nj = 0; nj < 4; ++nj)
            bf[nj] = *(const f16x8*)&Bs[cur][(wn + nj * 16 + (lane & 15)) * BK
                                            + (((lane >> 4) * 8) ^ swzR)];

        #pragma unroll
        for (int mi = 0; mi < 8; ++mi)
            #pragma unroll
            for (int nj = 0; nj < 4; ++nj)
                acc[mi][nj] = __builtin_amdgcn_mfma_f32_16x16x32_f16(
                    af[mi], bf[nj], acc[mi][nj], 0, 0, 0);

        __syncthreads();  // reads of buf[cur] done + stages into buf[cur^1] drained
        cur ^= 1;
    }

    // epilogue: D[m=(lane>>4)*4+r][n=lane&15] per 16x16 tile
    const float scale = sc[2];
    const int r0 = (int)rowA0 + wm + (lane >> 4) * 4;
    const int c0 = (int)rowB0 + wn + (lane & 15);
    #pragma unroll
    for (int nj = 0; nj < 4; ++nj) {
        const int col = c0 + nj * 16;
        const float b = bias[col];
        #pragma unroll
        for (int mi = 0; mi < 8; ++mi) {
            const int row = r0 + mi * 16;
            #pragma unroll
            for (int r = 0; r < 4; ++r)
                out[(long)(row + r) * OUTF + col] = acc[mi][nj][r] * scale + b;
        }
    }
}

extern "C" void kernel_launch(void* const* d_in, const int* in_sizes, int n_in,
                              void* d_out, int out_size, void* d_ws, size_t ws_size,
                              hipStream_t stream) {
    const float* input  = (const float*)d_in[0];   // [8192][4096]
    const float* weight = (const float*)d_in[1];   // [4096][4096]
    const float* wscale = (const float*)d_in[2];   // [1]
    const float* bias   = (const float*)d_in[3];   // [4096]
    float* out = (float*)d_out;

    float* scales   = (float*)d_ws;
    float* partials = (float*)((char*)d_ws + 16);
    _Float16* x_sum = (_Float16*)((char*)d_ws + 8208);
    _Float16* w_sum = (_Float16*)((char*)d_ws + 8208 + (size_t)NROWS * G * 2);

    pass1<<<3072, 256, 0, stream>>>((const float4*)input, (const float4*)weight,
                                    partials, w_sum);
    absmax_final<<<1, 256, 0, stream>>>(partials, wscale, scales);
    xquant<<<16384, 256, 0, stream>>>((const float4*)input, scales, x_sum);
    gemm_kernel<<<dim3(OUTF / BN, NROWS / BM), 256, 0, stream>>>(
        x_sum, w_sum, bias, scales, out);
}

// Round 2
// 374.676 us; speedup vs baseline: 1.0315x; 1.0315x over previous
//
#include <hip/hip_runtime.h>

// Problem constants
#define NROWS 8192
#define INF   4096
#define OUTF  4096
#define G     1024          // INF / 4

typedef _Float16 f16x8 __attribute__((ext_vector_type(8)));
typedef float    f32x4 __attribute__((ext_vector_type(4)));
typedef float    f32x4v __attribute__((ext_vector_type(4)));

// ws layout:
//   [0..16)                  float scales[3]: [0]=act_scale, [1]=unused, [2]=act_scale*0.25*wscale
//   [16 .. 16+8192)          2048 float block-partial maxes
//   [8208 ..)                x_sum f16 [NROWS][G]   (16 MB)
//   [8208 + NROWS*G*2 ..)    w_sum f16 [OUTF][G]    (8 MB)

// ---------- Kernel 1: absmax partials (x) + group-sum (w), one pass ----------
// blocks [0,2048): absmax over x, 16 float4/thread
// blocks [2048,3072): w group-sums, 16 float4/thread (scale-independent)
// w loads are NON-TEMPORAL: w is never read again; keep x resident in L3 for xquant.
__global__ void pass1(const float4* __restrict__ x,
                      const float4* __restrict__ w,
                      float* __restrict__ partial,
                      _Float16* __restrict__ ws) {
    const int t = threadIdx.x;
    const int b = blockIdx.x;
    if (b < 2048) {
        const int stride = 2048 * 256;
        int i = b * 256 + t;
        float m = 0.f;
        #pragma unroll 4
        for (int it = 0; it < 16; ++it, i += stride) {
            float4 v = x[i];
            m = fmaxf(m, fmaxf(fmaxf(fabsf(v.x), fabsf(v.y)),
                               fmaxf(fabsf(v.z), fabsf(v.w))));
        }
        for (int off = 32; off; off >>= 1)
            m = fmaxf(m, __shfl_down(m, off));
        __shared__ float wm[4];
        int lane = t & 63, wave = t >> 6;
        if (lane == 0) wm[wave] = m;
        __syncthreads();
        if (t == 0)
            partial[b] = fmaxf(fmaxf(wm[0], wm[1]), fmaxf(wm[2], wm[3]));
    } else {
        // 1024 blocks * 256 threads * 16 iters = 4194304 float4 groups of w
        int i = (b - 2048) * 4096 + t;
        #pragma unroll 4
        for (int it = 0; it < 16; ++it, i += 256) {
            f32x4v v = __builtin_nontemporal_load((const f32x4v*)&w[i]);
            ws[i] = (_Float16)(v.x + v.y + v.z + v.w);  // integer in [-4,4]: exact
        }
    }
}

// ---------- Kernel 2: reduce partials in-block + quantize + group-sum x ----------
// Every block re-reduces the 2048 partials (deterministic, identical result in all
// blocks; 8 KB L2-hit read) -- removes the separate 1-block reduce kernel.
// No clamps: absmax construction bounds |v*inv| <= 127*(1+eps) < 127.5, rint exact.
__global__ void xquant(const float4* __restrict__ x,
                       const float* __restrict__ partial,
                       const float* __restrict__ wscale,
                       float* __restrict__ sc,
                       _Float16* __restrict__ xs) {
    const int t = threadIdx.x;
    float m = 0.f;
    #pragma unroll
    for (int u = 0; u < 8; ++u)
        m = fmaxf(m, partial[t + u * 256]);
    for (int off = 32; off; off >>= 1)
        m = fmaxf(m, __shfl_down(m, off));
    __shared__ float wm[4];
    int lane = t & 63, wave = t >> 6;
    if (lane == 0) wm[wave] = m;
    __syncthreads();
    const float bm = fmaxf(fmaxf(wm[0], wm[1]), fmaxf(wm[2], wm[3]));
    const float inv = 127.0f / bm;
    if (blockIdx.x == 0 && t == 0) {
        float s = bm * (1.0f / 127.0f);
        sc[0] = s;                       // act_scale
        sc[2] = s * 0.25f * wscale[0];   // fused epilogue scale for GEMM
    }
    // 2048 blocks * 256 threads * 16 iters = 8388608 float4 groups
    int i = blockIdx.x * 4096 + t;
    #pragma unroll 4
    for (int it = 0; it < 16; ++it, i += 256) {
        float4 v = x[i];
        // per-group sum of quantized values: integer in [-512,508], exact in f16
        xs[i] = (_Float16)(rintf(v.x * inv) + rintf(v.y * inv) +
                           rintf(v.z * inv) + rintf(v.w * inv));
    }
}

// ---------- Kernel 3: f16 MFMA GEMM, 256x128 tile, triple-buffered depth-2 ----------
#define BM 256
#define BN 128
#define BK 32
#define NT (G / BK)   // 32 K-tiles

__device__ __forceinline__ void async_copy16(const void* g, void* l) {
    __builtin_amdgcn_global_load_lds(
        (const __attribute__((address_space(1))) unsigned int*)g,
        (__attribute__((address_space(3))) unsigned int*)l,
        16, 0, 0);
}

__global__ __launch_bounds__(256, 2) void gemm_kernel(
    const _Float16* __restrict__ A,
    const _Float16* __restrict__ B,
    const float* __restrict__ bias,
    const float* __restrict__ sc,
    float* __restrict__ out) {

    // Triple-buffered: 3 x (16 KB A + 8 KB B) = 72 KB -> still 2 blocks/CU (144<=160).
    __shared__ alignas(16) _Float16 As[3][BM * BK];
    __shared__ alignas(16) _Float16 Bs[3][BN * BK];

    const int t = threadIdx.x;
    const int lane = t & 63;
    const int wave = t >> 6;
    const int wm = (wave >> 1) * 128;   // wave tile: 128 rows x 64 cols
    const int wn = (wave & 1) * 64;

    // XCD-aware bijective swizzle: nwg = 32*32 = 1024, divisible by 8 XCDs.
    // Consecutive dispatch ids round-robin XCDs; give each XCD a contiguous chunk
    // (4 M-tile rows) so its private L2 keeps the A row-panels resident.
    const int lin = blockIdx.y * gridDim.x + blockIdx.x;
    const int swz = (lin & 7) * 128 + (lin >> 3);
    const int bx = swz & 31;            // N-tile
    const int by = swz >> 5;            // M-tile

    const long rowA0 = (long)by * BM;
    const long rowB0 = (long)bx * BN;

    f32x4 acc[8][4] = {};

    // Staging: chunk = 1 KB = 16 rows x 32 f16. Lane l covers row srow, 16 B at scol.
    // LDS dest linear (global_load_lds writes base + lane*16); bank-conflict swizzle
    // applied on the GLOBAL source column (both-sides rule):
    //   phys_col8 = col8 ^ ((row>>1)&3)<<3
    const int srow = lane >> 2;
    const int scol = ((lane & 3) << 3) ^ (((lane >> 3) & 3) << 3);
    const int swzR = ((lane >> 1) & 3) << 3;

    auto stage = [&](int buf, int kt) {
        const int k0 = kt * BK;
        #pragma unroll
        for (int i = 0; i < 6; ++i) {
            const int c = wave * 6 + i;       // wave-uniform chunk id, 24 = 16 A + 8 B
            if (c < 16) {
                const int row = c * 16 + srow;
                async_copy16(A + (rowA0 + row) * (long)G + k0 + scol, &As[buf][c * 512]);
            } else {
                const int row = (c - 16) * 16 + srow;
                async_copy16(B + (rowB0 + row) * (long)G + k0 + scol, &Bs[buf][(c - 16) * 512]);
            }
        }
    };

    // Depth-2 prefetch: tile k lives in buf k%3; its 6 loads only need to land at
    // iteration k (two compute-iterations of slack). Counted vmcnt keeps 12 loads
    // in flight across barriers -- never drain to 0 in the main loop (T4).
    stage(0, 0);
    stage(1, 1);

    int rb = 0;  // read buffer = ks % 3
    for (int ks = 0; ks < NT; ++ks) {
        if (ks + 2 < NT) {
            int sb = rb + 2; if (sb >= 3) sb -= 3;
            stage(sb, ks + 2);
        }
        // Drain exactly the loads for tile ks; keep younger tiles in flight.
        if (ks < NT - 2)       asm volatile("s_waitcnt vmcnt(12)" ::: "memory");
        else if (ks == NT - 2) asm volatile("s_waitcnt vmcnt(6)" ::: "memory");
        else                   asm volatile("s_waitcnt vmcnt(0)" ::: "memory");
        __builtin_amdgcn_s_barrier();   // all waves' tile-ks stages have landed

        f16x8 af[8], bf[4];
        #pragma unroll
        for (int mi = 0; mi < 8; ++mi)
            af[mi] = *(const f16x8*)&As[rb][(wm + mi * 16 + (lane & 15)) * BK
                                           + (((lane >> 4) * 8) ^ swzR)];
        #pragma unroll
        for (int nj = 0; nj < 4; ++nj)
            bf[nj] = *(const f16x8*)&Bs[rb][(wn + nj * 16 + (lane & 15)) * BK
                                           + (((lane >> 4) * 8) ^ swzR)];

        #pragma unroll
        for (int mi = 0; mi < 8; ++mi)
            #pragma unroll
            for (int nj = 0; nj < 4; ++nj)
                acc[mi][nj] = __builtin_amdgcn_mfma_f32_16x16x32_f16(
                    af[mi], bf[nj], acc[mi][nj], 0, 0, 0);

        __builtin_amdgcn_s_barrier();   // ds_reads of buf rb done before it is restaged
        ++rb; if (rb == 3) rb = 0;
    }

    // epilogue: D[m=(lane>>4)*4+r][n=lane&15] per 16x16 tile.
    // Non-temporal stores: out (134 MB) is never re-read; don't flush A/B/x from L2/L3.
    const float scale = sc[2];
    const int r0 = (int)rowA0 + wm + (lane >> 4) * 4;
    const int c0 = (int)rowB0 + wn + (lane & 15);
    #pragma unroll
    for (int nj = 0; nj < 4; ++nj) {
        const int col = c0 + nj * 16;
        const float b = bias[col];
        #pragma unroll
        for (int mi = 0; mi < 8; ++mi) {
            const int row = r0 + mi * 16;
            #pragma unroll
            for (int r = 0; r < 4; ++r)
                __builtin_nontemporal_store(acc[mi][nj][r] * scale + b,
                                            &out[(long)(row + r) * OUTF + col]);
        }
    }
}

extern "C" void kernel_launch(void* const* d_in, const int* in_sizes, int n_in,
                              void* d_out, int out_size, void* d_ws, size_t ws_size,
                              hipStream_t stream) {
    const float* input  = (const float*)d_in[0];   // [8192][4096]
    const float* weight = (const float*)d_in[1];   // [4096][4096]
    const float* wscale = (const float*)d_in[2];   // [1]
    const float* bias   = (const float*)d_in[3];   // [4096]
    float* out = (float*)d_out;

    float* scales   = (float*)d_ws;
    float* partials = (float*)((char*)d_ws + 16);
    _Float16* x_sum = (_Float16*)((char*)d_ws + 8208);
    _Float16* w_sum = (_Float16*)((char*)d_ws + 8208 + (size_t)NROWS * G * 2);

    pass1<<<3072, 256, 0, stream>>>((const float4*)input, (const float4*)weight,
                                    partials, w_sum);
    xquant<<<2048, 256, 0, stream>>>((const float4*)input, partials, wscale,
                                     scales, x_sum);
    gemm_kernel<<<dim3(OUTF / BN, NROWS / BM), 256, 0, stream>>>(
        x_sum, w_sum, bias, scales, out);
}